// Round 11
// baseline (182.475 us; speedup 1.0000x reference)
//
#include <hip/hip_runtime.h>
#include <hip/hip_bf16.h>

// SpikingSelfAttention — round 21: r20 base (batch-major XCD lists, MFMA
// Gram, k_red) + tail-kernel I/O cleanup:
//  - k_attn: Q tile staged to LDS with coalesced loads (was 16B frags at
//    1KB stride, 4x line inflation); STs written via LDS 64B line-drain
//    (was 8B us4 stores at 1KB stride).
//  - k_qkv q-path epilogue: LDS 64B line-drain (k/v already had it, r18).
// Pure data movement; MFMA order and all values bit-identical.

#define NB 8
#define NC 512
#define NT 4
#define NN 256
#define NL 1024
#define NH 8
#define ND 64
#define BCL (NB*NC*NL)

typedef __attribute__((ext_vector_type(8))) short  short8v;
typedef __attribute__((ext_vector_type(8))) unsigned short us8;
typedef __attribute__((ext_vector_type(4))) unsigned short us4;
typedef __attribute__((ext_vector_type(4))) float f32x4;

__device__ __forceinline__ float bu2f(unsigned short u) {
  return __uint_as_float(((unsigned)u) << 16);
}
__device__ __forceinline__ unsigned short f2bu(float f) {   // RNE f32->bf16
  unsigned b = __float_as_uint(f);
  return (unsigned short)((b + 0x7FFFu + ((b >> 16) & 1u)) >> 16);
}

// ---------------------------------------------------------------------------
// k_prep: blocks [0,512) = weight split into fragment-ordered H2;
//         blocks [512,1024) = proj BN+LIF -> ST0[b][l][c] bf16.
// H2 layout: offset = ((((p*3+j)*4+rt)*8+k0i)*8+chunk)*1024 + r*8
__global__ void k_prep(const float* __restrict__ wq, const float* __restrict__ wk,
                       const float* __restrict__ wv, const float* __restrict__ wp,
                       const float* __restrict__ x,
                       const float* __restrict__ g,  const float* __restrict__ bt,
                       const float* __restrict__ mu, const float* __restrict__ var,
                       unsigned short* __restrict__ H2,
                       unsigned short* __restrict__ ST0) {
  if (blockIdx.x < 512) {
    int gi = blockIdx.x * 256 + threadIdx.x;       // (p,o,k8): 4*512*64
    int p = gi >> 15;
    int o = (gi >> 6) & 511;
    int k8 = gi & 63;
    int rt = o >> 7, r = o & 127;
    int k0i = k8 >> 3, chunk = k8 & 7;
    const float* W = (p == 0) ? wq : (p == 1) ? wk : (p == 2) ? wv : wp;
    const float* src = W + (size_t)o * NC + k8 * 8;
    us8 a[3];
#pragma unroll
    for (int i = 0; i < 8; i++) {
      float w = src[i];
      unsigned short u1 = f2bu(w);
      float r1 = w - bu2f(u1);
      unsigned short u2 = f2bu(r1);
      float r2 = r1 - bu2f(u2);
      unsigned short u3 = f2bu(r2);
      a[0][i] = u1; a[1][i] = u2; a[2][i] = u3;
    }
#pragma unroll
    for (int j = 0; j < 3; j++) {
      size_t off = ((size_t)((((p * 3 + j) * 4 + rt) * 8 + k0i) * 8 + chunk)) * 1024
                   + (size_t)r * 8;
      *(us8*)&H2[off] = a[j];
    }
  } else {
    int bidx = blockIdx.x - 512;
    int b  = bidx >> 6;
    int c0 = (bidx & 63) * 8;
    int n  = threadIdx.x;
    unsigned short spk[NT][8];
#pragma unroll
    for (int i = 0; i < 8; i++) {
      int c = c0 + i;
      float inv = g[c] / sqrtf(var[c] + 1e-5f);
      float m = mu[c], be = bt[c];
      const float* xp = x + ((size_t)(b * NC + c)) * NL + n;
      float v = 0.f;
#pragma unroll
      for (int t = 0; t < NT; t++) {
        float y = (xp[t * NN] - m) * inv + be;
        v = v + (y - v) / 1.5f;
        unsigned short s = 0;
        if (v - 1.0f >= 0.f) { s = 0x3F80; v = 0.f; }
        spk[t][i] = s;
      }
    }
#pragma unroll
    for (int t = 0; t < NT; t++) {
      us8 pk;
#pragma unroll
      for (int i = 0; i < 8; i++) pk[i] = spk[t][i];
      *(us8*)&ST0[((size_t)b * NL + t * NN + n) * NC + c0] = pk;
    }
  }
}

// ---------------------------------------------------------------------------
// Fused q/k/v projection + BN + LIF. 16x16x32 MFMA, 128x128 tile, 4x1 wave
// strips. Batch-major XCD mapping (b = xcd) + A-register double-buffer.
// Epilogue: ALL paths LDS-staged to full 64B lines (q [l][c]; k,v [c][l]).
__global__ __launch_bounds__(256) void
k_qkv(const unsigned short* __restrict__ H2,
      const unsigned short* __restrict__ ST0,
      const float* __restrict__ gq, const float* __restrict__ bq,
      const float* __restrict__ mq, const float* __restrict__ vq,
      const float* __restrict__ gk, const float* __restrict__ bk,
      const float* __restrict__ mk, const float* __restrict__ vk,
      const float* __restrict__ gv, const float* __restrict__ bv,
      const float* __restrict__ mv, const float* __restrict__ vv,
      unsigned short* __restrict__ STq, unsigned short* __restrict__ STkT,
      unsigned short* __restrict__ STvT) {
  __shared__ __align__(16) unsigned short sB[2][128 * 64];

  int id = blockIdx.x;                  // 768 = 8 xcd * 96 slot
  int xcd = id & 7, slot = id >> 3;
  int b = xcd;                          // XCD-exclusive batch: ST0[b] L2-fits
  int grp = slot >> 3;                  // p*4+rt in [0,12)
  int p = grp >> 2, rt = grp & 3;
  int n0 = (slot & 7) * 32;

  int tid = threadIdx.x;
  int w = tid >> 6, lane = tid & 63, quad = lane >> 4, l15 = lane & 15;
  int xorv = l15 & 7;

  const unsigned short* Sb = ST0 + (size_t)b * NL * NC;
  const unsigned short* Hbase = H2 + ((size_t)((p * 3) * 4 + rt) * 8) * 8192;

  f32x4 acc[2][8];
#pragma unroll
  for (int ri = 0; ri < 2; ri++)
#pragma unroll
    for (int jj = 0; jj < 8; jj++) acc[ri][jj] = (f32x4){0.f, 0.f, 0.f, 0.f};

  // A-fragment double-buffer register sets (named, compile-time indexed).
  short8v A0[2][3][2], A1[2][3][2];

#define QLOADA(DST, K0I)                                                     \
  _Pragma("unroll") for (int ks = 0; ks < 2; ks++) {                         \
    int c8 = ks * 4 + quad;                                                  \
    _Pragma("unroll") for (int j = 0; j < 3; j++) {                          \
      const unsigned short* Hj =                                             \
          Hbase + ((size_t)(j * 4 * 8 + (K0I))) * 8192 + (size_t)c8 * 1024;  \
      DST[ks][j][0] = *(const short8v*)&Hj[(w * 32 + l15) * 8];              \
      DST[ks][j][1] = *(const short8v*)&Hj[(w * 32 + 16 + l15) * 8];         \
    }                                                                        \
  }

  QLOADA(A0, 0);                        // prologue A; latency hides under B-stage

  us8 breg[4];
  int ccs[4], segs[4];
  size_t bsrc[4];
#pragma unroll
  for (int i = 0; i < 4; i++) {
    int idx = tid + i * 256;
    int cc = idx >> 3, seg = idx & 7;
    int t = (cc >> 4) & 3, nn = (cc & 15) | ((cc >> 6) << 4);
    ccs[i] = cc; segs[i] = seg;
    bsrc[i] = (size_t)(t * NN + n0 + nn) * NC + seg * 8;
  }
#pragma unroll
  for (int i = 0; i < 4; i++) breg[i] = *(const us8*)&Sb[bsrc[i]];      // k0=0
#pragma unroll
  for (int i = 0; i < 4; i++)
    *(us8*)&sB[0][ccs[i] * 64 + ((segs[i] ^ (ccs[i] & 7)) << 3)] = breg[i];

#define QBPRE(K0N)                                                           \
  _Pragma("unroll") for (int i = 0; i < 4; i++)                              \
    breg[i] = *(const us8*)&Sb[bsrc[i] + (size_t)(K0N) * 64];

#define QBWRITE(BUFN)                                                        \
  _Pragma("unroll") for (int i = 0; i < 4; i++)                              \
    *(us8*)&sB[BUFN][ccs[i] * 64 + ((segs[i] ^ (ccs[i] & 7)) << 3)] = breg[i];

#define QMFMAS(AR, BUF)                                                      \
  _Pragma("unroll") for (int ks = 0; ks < 2; ks++) {                         \
    int c8 = ks * 4 + quad;                                                  \
    int poff = (c8 ^ xorv) << 3;                                             \
    short8v bf[8];                                                           \
    _Pragma("unroll") for (int jj = 0; jj < 8; jj++)                         \
      bf[jj] = *(const short8v*)&sB[BUF][(jj * 16 + l15) * 64 + poff];       \
    _Pragma("unroll") for (int j = 0; j < 3; j++)                            \
      _Pragma("unroll") for (int jj = 0; jj < 8; jj++) {                     \
        acc[0][jj] = __builtin_amdgcn_mfma_f32_16x16x32_bf16(                \
            AR[ks][j][0], bf[jj], acc[0][jj], 0, 0, 0);                      \
        acc[1][jj] = __builtin_amdgcn_mfma_f32_16x16x32_bf16(                \
            AR[ks][j][1], bf[jj], acc[1][jj], 0, 0, 0);                      \
      }                                                                      \
  }

#define QSTEP(K0I, ACUR, ANXT)                                               \
  __syncthreads();                                                           \
  { if ((K0I) < 7) { QLOADA(ANXT, (K0I) + 1); } }                            \
  { if ((K0I) < 7) { QBPRE((K0I) + 1); } }                                   \
  QMFMAS(ACUR, (K0I) & 1);                                                   \
  { if ((K0I) < 7) { QBWRITE(((K0I) & 1) ^ 1); } }

  QSTEP(0, A0, A1)
  QSTEP(1, A1, A0)
  QSTEP(2, A0, A1)
  QSTEP(3, A1, A0)
  QSTEP(4, A0, A1)
  QSTEP(5, A1, A0)
  QSTEP(6, A0, A1)
  QSTEP(7, A1, A0)

#undef QLOADA
#undef QBPRE
#undef QBWRITE
#undef QMFMAS
#undef QSTEP

  const float *g, *bb, *mpt, *vr;
  unsigned short* So;
  if (p == 0)      { g = gq; bb = bq; mpt = mq; vr = vq; So = STq; }
  else if (p == 1) { g = gk; bb = bk; mpt = mk; vr = vk; So = STkT; }
  else             { g = gv; bb = bv; mpt = mv; vr = vv; So = STvT; }
  So += (size_t)b * NL * NC;

  // Compute all spikes into registers first.
  unsigned short spa[2][2][4][4];       // [ri][nh][t][r]
#pragma unroll
  for (int ri = 0; ri < 2; ri++) {
    int ob = rt * 128 + w * 32 + ri * 16 + quad * 4;
    float av[4], mvv[4], bvv[4];
#pragma unroll
    for (int r = 0; r < 4; r++) {
      av[r]  = g[ob + r] / sqrtf(vr[ob + r] + 1e-5f);
      mvv[r] = mpt[ob + r];
      bvv[r] = bb[ob + r];
    }
#pragma unroll
    for (int nh = 0; nh < 2; nh++) {
#pragma unroll
      for (int r = 0; r < 4; r++) {
        float vmem = 0.f;
#pragma unroll
        for (int t = 0; t < NT; t++) {
          float y = (acc[ri][nh * 4 + t][r] - mvv[r]) * av[r] + bvv[r];
          vmem = vmem + (y - vmem) / 1.5f;
          unsigned short s = 0;
          if (vmem - 1.0f >= 0.f) { s = 0x3F80; vmem = 0.f; }
          spa[ri][nh][t][r] = s;
        }
      }
    }
  }

  __syncthreads();                      // K-loop sB reads done; safe to reuse
  unsigned short* sT = &sB[0][0];       // 32 KB scratch

  if (p == 0) {
    // Stage [l-local 128][c-local 128] (XOR-swizzled 16B chunks), then drain
    // 64B line segments: seg (l,4) -> So[l][rt*128 + seg*32 .. +32].
#pragma unroll
    for (int ri = 0; ri < 2; ri++)
#pragma unroll
      for (int nh = 0; nh < 2; nh++)
#pragma unroll
        for (int t = 0; t < 4; t++)
#pragma unroll
          for (int r = 0; r < 4; r++) {
            int lloc = t * 32 + (nh << 4) + l15;
            int col = w * 32 + ri * 16 + quad * 4 + r;
            int ch = col >> 3;
            int pch = (ch & 8) | ((ch & 7) ^ (lloc & 7));
            sT[lloc * 128 + (pch << 3) + (col & 7)] = spa[ri][nh][t][r];
          }
    __syncthreads();
#pragma unroll
    for (int ss = 0; ss < 2; ss++) {
      int s = tid + ss * 256;           // 512 segs = 128 lloc x 4 seg
      int lloc = s >> 2, seg = s & 3;
      int t = lloc >> 5, nn = lloc & 31;
      size_t rowg = (size_t)(t * NN + n0 + nn) * NC + rt * 128 + seg * 32;
#pragma unroll
      for (int i = 0; i < 4; i++) {
        int ch = seg * 4 + i;
        int pch = (ch & 8) | ((ch & 7) ^ (lloc & 7));
        us8 v = *(const us8*)&sT[lloc * 128 + (pch << 3)];
        *(us8*)&So[rowg + i * 8] = v;
      }
    }
  } else {
    // Stage [c 128][l-packed 128] tile in LDS (XOR-swizzled 16B granules),
    // then drain 64B full-line segments: seg (c,t) -> So[c][t*256+n0 .. +32].
#pragma unroll
    for (int ri = 0; ri < 2; ri++)
#pragma unroll
      for (int nh = 0; nh < 2; nh++)
#pragma unroll
        for (int t = 0; t < 4; t++)
#pragma unroll
          for (int r = 0; r < 4; r++) {
            int row = w * 32 + ri * 16 + quad * 4 + r;
            int col = t * 32 + (nh << 4) + l15;
            int phys = (((col >> 3) ^ (row & 7)) << 3) | (col & 7);
            sT[row * 128 + phys] = spa[ri][nh][t][r];
          }
    __syncthreads();
#pragma unroll
    for (int ss = 0; ss < 2; ss++) {
      int s = tid + ss * 256;           // 512 segs = 128 c x 4 t
      int c = s >> 2, t = s & 3;
#pragma unroll
      for (int i = 0; i < 4; i++) {
        int g8 = t * 4 + i;
        us8 v = *(const us8*)&sT[c * 128 + ((g8 ^ (c & 7)) << 3)];
        *(us8*)&So[(size_t)(rt * 128 + c) * NL + t * 256 + n0 + i * 8] = v;
      }
    }
  }
}

// ---------------------------------------------------------------------------
// MFMA Gram (chunked): Mpart[ch][bh][e][dd] = sum_{l in 128-chunk} K[l][e]*V[l][dd].
// KT/VT are [c][l] -> both fragments contiguous us8 loads; LDS-free.
// All products/sums are integers (spikes 0/1) -> fp32-exact, order-free.
__global__ __launch_bounds__(256) void
k_kvM(const unsigned short* __restrict__ STkT,
      const unsigned short* __restrict__ STvT,
      float* __restrict__ Mpart) {
  int bh = blockIdx.x, ch = blockIdx.y;       // ch 0..7
  int b = bh >> 3, h = bh & 7;
  const unsigned short* KT = STkT + ((size_t)(b * NC + h * ND)) * NL;
  const unsigned short* VT = STvT + ((size_t)(b * NC + h * ND)) * NL;
  int tid = threadIdx.x;
  int w = tid >> 6, lane = tid & 63, quad = lane >> 4, l15 = lane & 15;
  int lb = ch * 128;

  f32x4 acc[4];
#pragma unroll
  for (int jj = 0; jj < 4; jj++) acc[jj] = (f32x4){0.f, 0.f, 0.f, 0.f};

#pragma unroll
  for (int ks = 0; ks < 4; ks++) {
    int lc = lb + ks * 32 + quad * 8;
    short8v a = *(const short8v*)&KT[(size_t)(w * 16 + l15) * NL + lc];
#pragma unroll
    for (int jj = 0; jj < 4; jj++) {
      short8v bv = *(const short8v*)&VT[(size_t)(jj * 16 + l15) * NL + lc];
      acc[jj] = __builtin_amdgcn_mfma_f32_16x16x32_bf16(a, bv, acc[jj], 0, 0, 0);
    }
  }

  float* Mp = Mpart + ((size_t)ch * 64 + bh) * 4096;
#pragma unroll
  for (int jj = 0; jj < 4; jj++)
#pragma unroll
    for (int r = 0; r < 4; r++)
      Mp[(w * 16 + quad * 4 + r) * ND + jj * 16 + l15] = acc[jj][r];
}

// ---------------------------------------------------------------------------
// k_red: one-time reduction of Mpart's 8 chunks -> Msum[bh][e][dd].
// Integer-valued floats -> exact, order-preserving vs old in-k_attn reduce.
__global__ __launch_bounds__(256) void
k_red(const float* __restrict__ Mpart, float* __restrict__ Msum) {
  int i = blockIdx.x * 256 + threadIdx.x;     // 65536 float4 slots
  float4 s = ((const float4*)Mpart)[i];
#pragma unroll
  for (int ch = 1; ch < 8; ch++) {
    float4 t = ((const float4*)Mpart)[(size_t)ch * 65536 + i];
    s.x += t.x; s.y += t.y; s.z += t.z; s.w += t.w;
  }
  ((float4*)Msum)[i] = s;
}

// ---------------------------------------------------------------------------
// MFMA attention: O^T[dd][l] = sum_e (M1+M2)^T[dd][e] * Q[l][e]; spike O>=12.
// M split into two exact bf16 planes. Q tile staged to LDS coalesced; STs
// written via LDS 64B line-drain. Grid (8,64).
__global__ __launch_bounds__(256) void
k_attn(const unsigned short* __restrict__ STq,
       const float* __restrict__ Msum,
       unsigned short* __restrict__ STs) {
  __shared__ unsigned short MT1[64 * 64];   // [dd][e], 16B chunks phys = c ^ (dd&7)
  __shared__ unsigned short MT2[64 * 64];
  __shared__ unsigned short sQ[128 * 64];   // Q tile / spike stage (16 KB)
  int lt = blockIdx.x, bh = blockIdx.y;     // lt 0..7
  int b = bh >> 3, h = bh & 7;
  int tid = threadIdx.x;
  int w = tid >> 6, lane = tid & 63, quad = lane >> 4, l15 = lane & 15;

  const unsigned short* Qp = STq + (size_t)b * NL * NC + h * ND;

  // Stage Q tile: rows lt*128..+128, cols h*64..+64. Coalesced 16B loads,
  // XOR-swizzled chunk placement (row stride 128B -> needs swizzle).
#pragma unroll
  for (int i = 0; i < 4; i++) {
    int idx = tid + i * 256;            // 1024 = 128 rows x 8 chunks
    int row = idx >> 3, c8 = idx & 7;
    us8 v = *(const us8*)&Qp[(size_t)(lt * 128 + row) * NC + c8 * 8];
    *(us8*)&sQ[row * 64 + ((c8 ^ (row & 7)) << 3)] = v;
  }

#pragma unroll
  for (int i = 0; i < 4; i++) {
    int idx4 = tid + i * 256;
    float4 s = ((const float4*)Msum)[(size_t)bh * 1024 + idx4];
    int e = idx4 >> 4;
    int dd0 = (idx4 * 4) & 63;
    int chunk = e >> 3;
    float sv[4] = {s.x, s.y, s.z, s.w};
#pragma unroll
    for (int r = 0; r < 4; r++) {
      int dd = dd0 + r;
      unsigned short u1 = f2bu(sv[r]);
      unsigned short u2 = f2bu(sv[r] - bu2f(u1));
      int pos = dd * 64 + (((chunk ^ (dd & 7)) << 3) | (e & 7));
      MT1[pos] = u1;
      MT2[pos] = u2;
    }
  }
  __syncthreads();

  f32x4 acc[4][2];                           // [ddtile][ltile]
#pragma unroll
  for (int dt = 0; dt < 4; dt++)
#pragma unroll
    for (int j = 0; j < 2; j++) acc[dt][j] = (f32x4){0.f, 0.f, 0.f, 0.f};

#pragma unroll
  for (int ks = 0; ks < 2; ks++) {
    short8v bq[2];
#pragma unroll
    for (int ltile = 0; ltile < 2; ltile++) {
      int row = w * 32 + ltile * 16 + l15;
      bq[ltile] = *(const short8v*)&sQ[row * 64
                                       + (((ks * 4 + quad) ^ (row & 7)) << 3)];
    }
    int c8 = ks * 4 + quad;
#pragma unroll
    for (int dt = 0; dt < 4; dt++) {
      int dd = dt * 16 + l15;
      int off = dd * 64 + ((c8 ^ (dd & 7)) << 3);
      short8v a1 = *(const short8v*)&MT1[off];
      short8v a2 = *(const short8v*)&MT2[off];
#pragma unroll
      for (int ltile = 0; ltile < 2; ltile++) {
        acc[dt][ltile] = __builtin_amdgcn_mfma_f32_16x16x32_bf16(a1, bq[ltile], acc[dt][ltile], 0, 0, 0);
        acc[dt][ltile] = __builtin_amdgcn_mfma_f32_16x16x32_bf16(a2, bq[ltile], acc[dt][ltile], 0, 0, 0);
      }
    }
  }

  __syncthreads();                      // all sQ reads done; reuse as stage
#pragma unroll
  for (int dt = 0; dt < 4; dt++)
#pragma unroll
    for (int ltile = 0; ltile < 2; ltile++) {
      int row = w * 32 + ltile * 16 + l15;
#pragma unroll
      for (int r = 0; r < 4; r++) {
        int col = dt * 16 + quad * 4 + r;
        int phys = (((col >> 3) ^ (row & 7)) << 3) | (col & 7);
        sQ[row * 64 + phys] = (acc[dt][ltile][r] >= 12.0f) ? 0x3F80 : 0;
      }
    }
  __syncthreads();

  unsigned short* Sp = STs + (size_t)b * NL * NC + h * ND;
  {
    int row = tid >> 1, seg = tid & 1;  // 256 segs = 128 rows x 2 (64B each)
    size_t dst = (size_t)(lt * 128 + row) * NC + seg * 32;
#pragma unroll
    for (int i = 0; i < 4; i++) {
      int ch = seg * 4 + i;
      us8 v = *(const us8*)&sQ[row * 64 + ((ch ^ (row & 7)) << 3)];
      *(us8*)&Sp[dst + i * 8] = v;
    }
  }
}

// ---------------------------------------------------------------------------
// Final projection: 16x16x32, 128 rows x 64 cols; batch-major XCD mapping
// (b = xcd) + A-register double-buffer.
__global__ __launch_bounds__(256) void
k_out(const unsigned short* __restrict__ H2,
      const unsigned short* __restrict__ STs,
      const float* __restrict__ bp, float* __restrict__ out) {
  __shared__ __align__(16) unsigned short sB[2][64 * 64];

  int id = blockIdx.x;                  // 512 = 8 xcd * 64 slot
  int xcd = id & 7, slot = id >> 3;
  int b  = xcd;                         // XCD-exclusive batch: STs[b] L2-fits
  int rt = slot >> 4;
  int l0 = (slot & 15) * 64;

  int tid = threadIdx.x;
  int w = tid >> 6, lane = tid & 63, quad = lane >> 4, l15 = lane & 15;
  int xorv = l15 & 7;

  const unsigned short* Sb = STs + (size_t)b * NL * NC;
  const unsigned short* Hbase = H2 + ((size_t)(9 * 4 + rt) * 8) * 8192;  // p=3

  f32x4 acc[2][4];
#pragma unroll
  for (int ri = 0; ri < 2; ri++)
#pragma unroll
    for (int jj = 0; jj < 4; jj++) acc[ri][jj] = (f32x4){0.f, 0.f, 0.f, 0.f};

  short8v A0[2][3][2], A1[2][3][2];

#define OLOADA(DST, K0I)                                                     \
  _Pragma("unroll") for (int ks = 0; ks < 2; ks++) {                         \
    int c8 = ks * 4 + quad;                                                  \
    _Pragma("unroll") for (int j = 0; j < 3; j++) {                          \
      const unsigned short* Hj =                                             \
          Hbase + ((size_t)(j * 4 * 8 + (K0I))) * 8192 + (size_t)c8 * 1024;  \
      DST[ks][j][0] = *(const short8v*)&Hj[(w * 32 + l15) * 8];              \
      DST[ks][j][1] = *(const short8v*)&Hj[(w * 32 + 16 + l15) * 8];         \
    }                                                                        \
  }

  OLOADA(A0, 0);

  us8 breg[2];
  int ccs[2], segs[2];
  size_t bsrc[2];
#pragma unroll
  for (int i = 0; i < 2; i++) {
    int idx = tid + i * 256;
    int cc = idx >> 3, seg = idx & 7;
    ccs[i] = cc; segs[i] = seg;
    bsrc[i] = (size_t)(l0 + cc) * NC + seg * 8;
  }
#pragma unroll
  for (int i = 0; i < 2; i++) breg[i] = *(const us8*)&Sb[bsrc[i]];
#pragma unroll
  for (int i = 0; i < 2; i++)
    *(us8*)&sB[0][ccs[i] * 64 + ((segs[i] ^ (ccs[i] & 7)) << 3)] = breg[i];

#define OBPRE(K0N)                                                           \
  _Pragma("unroll") for (int i = 0; i < 2; i++)                              \
    breg[i] = *(const us8*)&Sb[bsrc[i] + (size_t)(K0N) * 64];

#define OBWRITE(BUFN)                                                        \
  _Pragma("unroll") for (int i = 0; i < 2; i++)                              \
    *(us8*)&sB[BUFN][ccs[i] * 64 + ((segs[i] ^ (ccs[i] & 7)) << 3)] = breg[i];

#define OMFMAS(AR, BUF)                                                      \
  _Pragma("unroll") for (int ks = 0; ks < 2; ks++) {                         \
    int c8 = ks * 4 + quad;                                                  \
    int poff = (c8 ^ xorv) << 3;                                             \
    short8v bf[4];                                                           \
    _Pragma("unroll") for (int jj = 0; jj < 4; jj++)                         \
      bf[jj] = *(const short8v*)&sB[BUF][(jj * 16 + l15) * 64 + poff];       \
    _Pragma("unroll") for (int j = 0; j < 3; j++)                            \
      _Pragma("unroll") for (int jj = 0; jj < 4; jj++) {                     \
        acc[0][jj] = __builtin_amdgcn_mfma_f32_16x16x32_bf16(                \
            AR[ks][j][0], bf[jj], acc[0][jj], 0, 0, 0);                      \
        acc[1][jj] = __builtin_amdgcn_mfma_f32_16x16x32_bf16(                \
            AR[ks][j][1], bf[jj], acc[1][jj], 0, 0, 0);                      \
      }                                                                      \
  }

#define OSTEP(K0I, ACUR, ANXT)                                               \
  __syncthreads();                                                           \
  { if ((K0I) < 7) { OLOADA(ANXT, (K0I) + 1); } }                            \
  { if ((K0I) < 7) { OBPRE((K0I) + 1); } }                                   \
  OMFMAS(ACUR, (K0I) & 1);                                                   \
  { if ((K0I) < 7) { OBWRITE(((K0I) & 1) ^ 1); } }

  OSTEP(0, A0, A1)
  OSTEP(1, A1, A0)
  OSTEP(2, A0, A1)
  OSTEP(3, A1, A0)
  OSTEP(4, A0, A1)
  OSTEP(5, A1, A0)
  OSTEP(6, A0, A1)
  OSTEP(7, A1, A0)

#undef OLOADA
#undef OBPRE
#undef OBWRITE
#undef OMFMAS
#undef OSTEP

#pragma unroll
  for (int ri = 0; ri < 2; ri++) {
    int ob = rt * 128 + w * 32 + ri * 16 + quad * 4;
#pragma unroll
    for (int jj = 0; jj < 4; jj++) {
      int l = l0 + jj * 16 + l15;
#pragma unroll
      for (int r = 0; r < 4; r++)
        out[((size_t)(b * NC + ob + r)) * NL + l] = acc[ri][jj][r] + bp[ob + r];
    }
  }
}

// ---------------------------------------------------------------------------
extern "C" void kernel_launch(void* const* d_in, const int* in_sizes, int n_in,
                              void* d_out, int out_size, void* d_ws, size_t ws_size,
                              hipStream_t stream) {
  (void)in_sizes; (void)n_in; (void)out_size; (void)ws_size;
  const float* x   = (const float*)d_in[0];
  const float* wq  = (const float*)d_in[1];
  const float* wk  = (const float*)d_in[2];
  const float* wv  = (const float*)d_in[3];
  const float* wp  = (const float*)d_in[4];
  const float* bp  = (const float*)d_in[5];
  const float* gq  = (const float*)d_in[6];
  const float* bq  = (const float*)d_in[7];
  const float* mq  = (const float*)d_in[8];
  const float* vq  = (const float*)d_in[9];
  const float* gk  = (const float*)d_in[10];
  const float* bk  = (const float*)d_in[11];
  const float* mk  = (const float*)d_in[12];
  const float* vk  = (const float*)d_in[13];
  const float* gv  = (const float*)d_in[14];
  const float* bv  = (const float*)d_in[15];
  const float* mv  = (const float*)d_in[16];
  const float* vvv = (const float*)d_in[17];
  const float* gp  = (const float*)d_in[18];
  const float* bpn = (const float*)d_in[19];
  const float* mp  = (const float*)d_in[20];
  const float* vp  = (const float*)d_in[21];

  unsigned short* H2   = (unsigned short*)d_ws;
  unsigned short* ST0  = H2 + (size_t)4 * 3 * NC * NC;
  unsigned short* STq  = ST0 + BCL;
  unsigned short* STkT = STq + BCL;
  unsigned short* STvT = STkT + BCL;
  unsigned short* STs  = STvT + BCL;
  float* Mpart = (float*)(STs + BCL);   // 8 * 64 * 4096 floats
  float* Msum  = Mpart + (size_t)8 * 64 * 4096;  // 64 * 4096 floats

  dim3 blk(256);
  k_prep<<<1024, blk, 0, stream>>>(wq, wk, wv, wp, x, gp, bpn, mp, vp, H2, ST0);
  k_qkv<<<768, blk, 0, stream>>>(H2, ST0,
      gq, bq, mq, vq, gk, bk, mk, vk, gv, bv, mv, vvv, STq, STkT, STvT);
  k_kvM<<<dim3(64, 8), blk, 0, stream>>>(STkT, STvT, Mpart);
  k_red<<<256, blk, 0, stream>>>(Mpart, Msum);
  k_attn<<<dim3(8, 64), blk, 0, stream>>>(STq, Msum, STs);
  k_out<<<512, blk, 0, stream>>>(H2, STs, bp, (float*)d_out);
}